// Round 1
// baseline (849.717 us; speedup 1.0000x reference)
//
#include <hip/hip_runtime.h>
#include <cstdint>

// MultiHeadSelfAttention: N=2, L=2048, E=1024, H=16, D=64, f32 in/out.
// Round 0: all-f32 vector-ALU baseline (no fp32 MFMA exists on CDNA4).
// Pipeline: proj(q,k,v) -> flash attention (online softmax, mask) -> out proj.
// d_ws layout: Q | K | V | AO, each N*L*E floats = 16 MiB (64 MiB total).

#define NB 2
#define LSEQ 2048
#define EMB 1024
#define NHEADS 16
#define HD 64

// acc[i][j] += A.i * B.j  (outer product 4x4)
#define FMA16(ACC, A, B)                                \
  do {                                                  \
    ACC[0][0] = fmaf((A).x, (B).x, ACC[0][0]);          \
    ACC[0][1] = fmaf((A).x, (B).y, ACC[0][1]);          \
    ACC[0][2] = fmaf((A).x, (B).z, ACC[0][2]);          \
    ACC[0][3] = fmaf((A).x, (B).w, ACC[0][3]);          \
    ACC[1][0] = fmaf((A).y, (B).x, ACC[1][0]);          \
    ACC[1][1] = fmaf((A).y, (B).y, ACC[1][1]);          \
    ACC[1][2] = fmaf((A).y, (B).z, ACC[1][2]);          \
    ACC[1][3] = fmaf((A).y, (B).w, ACC[1][3]);          \
    ACC[2][0] = fmaf((A).z, (B).x, ACC[2][0]);          \
    ACC[2][1] = fmaf((A).z, (B).y, ACC[2][1]);          \
    ACC[2][2] = fmaf((A).z, (B).z, ACC[2][2]);          \
    ACC[2][3] = fmaf((A).z, (B).w, ACC[2][3]);          \
    ACC[3][0] = fmaf((A).w, (B).x, ACC[3][0]);          \
    ACC[3][1] = fmaf((A).w, (B).y, ACC[3][1]);          \
    ACC[3][2] = fmaf((A).w, (B).z, ACC[3][2]);          \
    ACC[3][3] = fmaf((A).w, (B).w, ACC[3][3]);          \
  } while (0)

// Thread mapping shared by all GEMM-like phases (256 threads):
//   lane = t & 63, w = t >> 6
//   c0 = (lane & 15) * 4           -> 16 column groups of 4 (float4 reads)
//   r0 = ((lane >> 4) & 3)*4 + w*16 -> 4 row groups per wave
// LDS operand tiles stored TRANSPOSED ([k-dim][row/col]) so both operands are
// contiguous float4 at each k step; reads are broadcast/2-way (free).

// ---------------------------------------------------------------------------
// Per-head projection: out[nh][l][d] = sum_e x[n][l][h*64+e] * W[d][e]
// One block = one (n,h) and 64 l-rows.
__global__ __launch_bounds__(256) void proj_kernel(
    const float* __restrict__ x,   // [N][L][E]
    const float* __restrict__ W,   // [64][64] row-major W[d][e]
    float* __restrict__ out)       // [N*H][L][64]
{
  __shared__ __align__(16) float wT[64 * 64];  // wT[e][d] = W[d][e]
  __shared__ __align__(16) float xT[64 * 64];  // xT[e][r] = x[l0+r][h*64+e]
  const int t = threadIdx.x;
  const int w = t >> 6, lane = t & 63;
  const int nh = blockIdx.y;
  const int n = nh >> 4, h = nh & 15;
  const int l0 = blockIdx.x * 64;

  // Load W transposed: thread reads row d=lane, e-chunk w*16..w*16+15.
  {
    const float* wrow = W + lane * 64 + w * 16;
#pragma unroll
    for (int i = 0; i < 4; ++i) {
      float4 v = *(const float4*)(wrow + i * 4);
      int e = w * 16 + i * 4;
      wT[(e + 0) * 64 + lane] = v.x;
      wT[(e + 1) * 64 + lane] = v.y;
      wT[(e + 2) * 64 + lane] = v.z;
      wT[(e + 3) * 64 + lane] = v.w;
    }
  }
  // Load x tile transposed: thread reads row l0+lane, e-chunk w*16..+15.
  {
    const float* xrow =
        x + ((size_t)n * LSEQ + l0 + lane) * EMB + h * HD + w * 16;
#pragma unroll
    for (int i = 0; i < 4; ++i) {
      float4 v = *(const float4*)(xrow + i * 4);
      int e = w * 16 + i * 4;
      xT[(e + 0) * 64 + lane] = v.x;
      xT[(e + 1) * 64 + lane] = v.y;
      xT[(e + 2) * 64 + lane] = v.z;
      xT[(e + 3) * 64 + lane] = v.w;
    }
  }
  __syncthreads();

  const int c0 = (lane & 15) * 4;
  const int r0 = ((lane >> 4) & 3) * 4 + w * 16;
  float acc[4][4] = {};
#pragma unroll 8
  for (int e = 0; e < 64; ++e) {
    float4 xv = *(const float4*)&xT[e * 64 + r0];
    float4 wv = *(const float4*)&wT[e * 64 + c0];
    FMA16(acc, xv, wv);
  }

  float* ob = out + ((size_t)nh * LSEQ + l0) * HD;
#pragma unroll
  for (int i = 0; i < 4; ++i) {
    float4 r = make_float4(acc[i][0], acc[i][1], acc[i][2], acc[i][3]);
    *(float4*)&ob[(size_t)(r0 + i) * HD + c0] = r;
  }
}

// ---------------------------------------------------------------------------
// Flash-style attention for one (n,h,q-tile of 64 rows).
// S = Q K^T; masked logit = -1e20 * (1/32) = -3.125e18 (matches reference,
// which masks BEFORE the /sqrt(E) scale). Online softmax; O accumulated in
// registers; P handed S->O through LDS with a 4-granular column swizzle.
__global__ __launch_bounds__(256) void attn_kernel(
    const float* __restrict__ Q,   // [N*H][L][64]
    const float* __restrict__ K,   // [N*H][L][64]
    const float* __restrict__ V,   // [N*H][L][64]
    const int* __restrict__ mask,  // [N][L]
    float* __restrict__ O)         // [N][L][E] (E index = h*64+d)
{
  __shared__ __align__(16) float qT[64 * 64];  // qT[d][q]
  __shared__ __align__(16) float kT[64 * 64];  // kT[d][k]
  __shared__ __align__(16) float vs[64 * 64];  // vs[k][d] row-major
  __shared__ __align__(16) float pT[64 * 64];  // pT[k][swizzled q]
  const int t = threadIdx.x;
  const int w = t >> 6, lane = t & 63;
  const int nh = blockIdx.y;
  const int n = nh >> 4, h = nh & 15;
  const int q0g = blockIdx.x * 64;

  // Load Q tile transposed (row q=lane, d-chunk w*16..+15).
  {
    const float* qb = Q + ((size_t)nh * LSEQ + q0g + lane) * HD + w * 16;
#pragma unroll
    for (int i = 0; i < 4; ++i) {
      float4 v = *(const float4*)(qb + i * 4);
      int d = w * 16 + i * 4;
      qT[(d + 0) * 64 + lane] = v.x;
      qT[(d + 1) * 64 + lane] = v.y;
      qT[(d + 2) * 64 + lane] = v.z;
      qT[(d + 3) * 64 + lane] = v.w;
    }
  }

  const int c0 = (lane & 15) * 4;                // S: k cols / O: d cols
  const int r0 = ((lane >> 4) & 3) * 4 + w * 16; // q rows (same both phases)
  const float scale = 0.03125f;                  // 1/sqrt(1024)
  const float MASKED = -3.125e18f;               // -1e20 / 32

  float m_i[4], l_i[4], o[4][4] = {};
#pragma unroll
  for (int i = 0; i < 4; ++i) { m_i[i] = -3.4e38f; l_i[i] = 0.0f; }

  for (int kt = 0; kt < LSEQ / 64; ++kt) {
    __syncthreads();  // previous O-phase done with vs/pT (and kT free)
    // Load K tile transposed.
    {
      const float* kb =
          K + ((size_t)nh * LSEQ + kt * 64 + lane) * HD + w * 16;
#pragma unroll
      for (int i = 0; i < 4; ++i) {
        float4 v = *(const float4*)(kb + i * 4);
        int d = w * 16 + i * 4;
        kT[(d + 0) * 64 + lane] = v.x;
        kT[(d + 1) * 64 + lane] = v.y;
        kT[(d + 2) * 64 + lane] = v.z;
        kT[(d + 3) * 64 + lane] = v.w;
      }
    }
    // Load V tile row-major (linear coalesced copy).
    {
      const float* vb = V + ((size_t)nh * LSEQ + kt * 64) * HD;
#pragma unroll
      for (int c = 0; c < 4; ++c) {
        int f = (c * 256 + t) * 4;
        *(float4*)&vs[f] = *(const float4*)(vb + f);
      }
    }
    __syncthreads();

    // ---- S phase: s[i][j] = sum_d Q[r0+i][d] * K[c0+j][d]
    float s[4][4] = {};
#pragma unroll 8
    for (int d = 0; d < 64; ++d) {
      float4 qv = *(const float4*)&qT[d * 64 + r0];
      float4 kv = *(const float4*)&kT[d * 64 + c0];
      FMA16(s, qv, kv);
    }

    // Mask + scale (mask==0 -> -1e20, then /32).
    const int* mrow = mask + n * LSEQ + kt * 64 + c0;
    int mk[4];
#pragma unroll
    for (int j = 0; j < 4; ++j) mk[j] = mrow[j];
#pragma unroll
    for (int i = 0; i < 4; ++i)
#pragma unroll
      for (int j = 0; j < 4; ++j)
        s[i][j] = (mk[j] != 0) ? s[i][j] * scale : MASKED;

    // Row max across j and the 16 lanes sharing this row group.
    float rmax[4];
#pragma unroll
    for (int i = 0; i < 4; ++i)
      rmax[i] = fmaxf(fmaxf(s[i][0], s[i][1]), fmaxf(s[i][2], s[i][3]));
#pragma unroll
    for (int off = 1; off < 16; off <<= 1)
#pragma unroll
      for (int i = 0; i < 4; ++i)
        rmax[i] = fmaxf(rmax[i], __shfl_xor(rmax[i], off));

    // Online softmax update.
    float alpha[4], p[4][4], rs[4];
#pragma unroll
    for (int i = 0; i < 4; ++i) {
      float mn = fmaxf(m_i[i], rmax[i]);
      alpha[i] = __expf(m_i[i] - mn);
      m_i[i] = mn;
#pragma unroll
      for (int j = 0; j < 4; ++j) p[i][j] = __expf(s[i][j] - mn);
      rs[i] = (p[i][0] + p[i][1]) + (p[i][2] + p[i][3]);
    }
#pragma unroll
    for (int off = 1; off < 16; off <<= 1)
#pragma unroll
      for (int i = 0; i < 4; ++i) rs[i] += __shfl_xor(rs[i], off);
#pragma unroll
    for (int i = 0; i < 4; ++i) l_i[i] = l_i[i] * alpha[i] + rs[i];

    // Write P transposed+swizzled: pT[k][((q/4 + k/4)&15)*4 + i] = P[q][k].
#pragma unroll
    for (int j = 0; j < 4; ++j) {
      int k = c0 + j;
      int col = (((r0 >> 2) + (k >> 2)) & 15) * 4;
      float4 pv = make_float4(p[0][j], p[1][j], p[2][j], p[3][j]);
      *(float4*)&pT[k * 64 + col] = pv;
    }
    __syncthreads();

    // ---- O phase: o[i][c] = o[i][c]*alpha + sum_k P[r0+i][k] * V[k][c0+c]
#pragma unroll
    for (int i = 0; i < 4; ++i)
#pragma unroll
      for (int c = 0; c < 4; ++c) o[i][c] *= alpha[i];
#pragma unroll 8
    for (int k = 0; k < 64; ++k) {
      float4 vv = *(const float4*)&vs[k * 64 + c0];
      int col = (((r0 >> 2) + (k >> 2)) & 15) * 4;
      float4 pv = *(const float4*)&pT[k * 64 + col];
      FMA16(o, pv, vv);
    }
  }

  // Epilogue: normalize and write [n][l][h*64+d].
  float* ob = O + ((size_t)n * LSEQ + q0g) * EMB + (size_t)h * HD;
#pragma unroll
  for (int i = 0; i < 4; ++i) {
    float inv = 1.0f / l_i[i];
    float4 r = make_float4(o[i][0] * inv, o[i][1] * inv, o[i][2] * inv,
                           o[i][3] * inv);
    *(float4*)&ob[(size_t)(r0 + i) * EMB + c0] = r;
  }
}

// ---------------------------------------------------------------------------
// Output projection: C[r][j] = sum_e A[r][e] * Wo[j][e] + bo[j]
// 64x64 output tile per block, K=1024 in chunks of 64.
__global__ __launch_bounds__(256) void outproj_kernel(
    const float* __restrict__ A,   // [N*L][E]
    const float* __restrict__ Wo,  // [E][E] row-major Wo[j][e]
    const float* __restrict__ bo,  // [E]
    float* __restrict__ C)         // [N*L][E]
{
  __shared__ __align__(16) float aT[64 * 64];  // aT[e][r]
  __shared__ __align__(16) float wT[64 * 64];  // wT[e][j]
  const int t = threadIdx.x;
  const int w = t >> 6, lane = t & 63;
  const int j0g = blockIdx.x * 64;  // 16 tiles
  const int r0g = blockIdx.y * 64;  // 64 tiles
  const int c0 = (lane & 15) * 4;
  const int r0 = ((lane >> 4) & 3) * 4 + w * 16;

  float acc[4][4] = {};
  for (int ek = 0; ek < EMB; ek += 64) {
    __syncthreads();
    {
      const float* ab = A + (size_t)(r0g + lane) * EMB + ek + w * 16;
#pragma unroll
      for (int i = 0; i < 4; ++i) {
        float4 v = *(const float4*)(ab + i * 4);
        int e = w * 16 + i * 4;
        aT[(e + 0) * 64 + lane] = v.x;
        aT[(e + 1) * 64 + lane] = v.y;
        aT[(e + 2) * 64 + lane] = v.z;
        aT[(e + 3) * 64 + lane] = v.w;
      }
      const float* wb = Wo + (size_t)(j0g + lane) * EMB + ek + w * 16;
#pragma unroll
      for (int i = 0; i < 4; ++i) {
        float4 v = *(const float4*)(wb + i * 4);
        int e = w * 16 + i * 4;
        wT[(e + 0) * 64 + lane] = v.x;
        wT[(e + 1) * 64 + lane] = v.y;
        wT[(e + 2) * 64 + lane] = v.z;
        wT[(e + 3) * 64 + lane] = v.w;
      }
    }
    __syncthreads();
#pragma unroll 8
    for (int e = 0; e < 64; ++e) {
      float4 av = *(const float4*)&aT[e * 64 + r0];
      float4 wv = *(const float4*)&wT[e * 64 + c0];
      FMA16(acc, av, wv);
    }
  }

  float4 b4 = *(const float4*)&bo[j0g + c0];
  float* cb = C + (size_t)r0g * EMB + j0g;
#pragma unroll
  for (int i = 0; i < 4; ++i) {
    float4 r = make_float4(acc[i][0] + b4.x, acc[i][1] + b4.y,
                           acc[i][2] + b4.z, acc[i][3] + b4.w);
    *(float4*)&cb[(size_t)(r0 + i) * EMB + c0] = r;
  }
}

// ---------------------------------------------------------------------------
extern "C" void kernel_launch(void* const* d_in, const int* in_sizes, int n_in,
                              void* d_out, int out_size, void* d_ws,
                              size_t ws_size, hipStream_t stream) {
  const float* values = (const float*)d_in[0];
  const float* keys   = (const float*)d_in[1];
  const float* query  = (const float*)d_in[2];
  const int*   mask   = (const int*)d_in[3];
  const float* Wv     = (const float*)d_in[4];
  const float* Wk     = (const float*)d_in[5];
  const float* Wq     = (const float*)d_in[6];
  const float* Wo     = (const float*)d_in[7];
  const float* bo     = (const float*)d_in[8];
  float* out = (float*)d_out;

  float* ws = (float*)d_ws;
  const size_t tsz = (size_t)NB * LSEQ * EMB;  // 4 Mi floats = 16 MiB
  float* Qb = ws + 0 * tsz;
  float* Kb = ws + 1 * tsz;
  float* Vb = ws + 2 * tsz;
  float* AO = ws + 3 * tsz;  // needs 64 MiB of d_ws total

  dim3 blk(256);
  // grid: (l-tiles, n*h)
  proj_kernel<<<dim3(LSEQ / 64, NB * NHEADS), blk, 0, stream>>>(query, Wq, Qb);
  proj_kernel<<<dim3(LSEQ / 64, NB * NHEADS), blk, 0, stream>>>(keys, Wk, Kb);
  proj_kernel<<<dim3(LSEQ / 64, NB * NHEADS), blk, 0, stream>>>(values, Wv, Vb);
  attn_kernel<<<dim3(LSEQ / 64, NB * NHEADS), blk, 0, stream>>>(Qb, Kb, Vb,
                                                                mask, AO);
  outproj_kernel<<<dim3(EMB / 64, (NB * LSEQ) / 64), blk, 0, stream>>>(
      AO, Wo, bo, out);
}

// Round 2
// 258.444 us; speedup vs baseline: 3.2878x; 3.2878x over previous
//
#include <hip/hip_runtime.h>
#include <hip/hip_bf16.h>
#include <cstdint>

// MultiHeadSelfAttention N=2,L=2048,E=1024,H=16,D=64.
// Round 2: bf16 MFMA attention (S^T scheme) + bf16 MFMA out-projection.
// f32 projections -> bf16 Q,K [nh][L][64], V^T [nh][64][L]
// attn: per wave 64 q-rows, S^T = K·Q^T via mfma_16x16x32_bf16, online softmax,
// P packed bf16 -> wave-private LDS tile -> PV MFMA. AO written bf16.
// outproj: 128x128-tile bf16 MFMA GEMM (+bias), f32 out.

#define NB 2
#define LSEQ 2048
#define EMB 1024
#define NHEADS 16
#define HD 64

using short8 = __attribute__((ext_vector_type(8))) short;
using short4v = __attribute__((ext_vector_type(4))) short;
using f32x4 = __attribute__((ext_vector_type(4))) float;

__device__ inline short bf16of(float f) {
  union { __hip_bfloat16 b; short s; } u;
  u.b = __float2bfloat16(f);
  return u.s;
}

__device__ inline short4v pack4bf(float a, float b, float c, float d) {
  union { __hip_bfloat162 v[2]; short4v s; } u;
  u.v[0] = __float22bfloat162_rn(make_float2(a, b));
  u.v[1] = __float22bfloat162_rn(make_float2(c, d));
  return u.s;
}

#define MFMA(A, B, C) __builtin_amdgcn_mfma_f32_16x16x32_bf16((A), (B), (C), 0, 0, 0)

// acc[i][j] += A.i * B.j  (outer product 4x4) -- f32 projections
#define FMA16(ACC, A, B)                       \
  do {                                         \
    ACC[0][0] = fmaf((A).x, (B).x, ACC[0][0]); \
    ACC[0][1] = fmaf((A).x, (B).y, ACC[0][1]); \
    ACC[0][2] = fmaf((A).x, (B).z, ACC[0][2]); \
    ACC[0][3] = fmaf((A).x, (B).w, ACC[0][3]); \
    ACC[1][0] = fmaf((A).y, (B).x, ACC[1][0]); \
    ACC[1][1] = fmaf((A).y, (B).y, ACC[1][1]); \
    ACC[1][2] = fmaf((A).y, (B).z, ACC[1][2]); \
    ACC[1][3] = fmaf((A).y, (B).w, ACC[1][3]); \
    ACC[2][0] = fmaf((A).z, (B).x, ACC[2][0]); \
    ACC[2][1] = fmaf((A).z, (B).y, ACC[2][1]); \
    ACC[2][2] = fmaf((A).z, (B).z, ACC[2][2]); \
    ACC[2][3] = fmaf((A).z, (B).w, ACC[2][3]); \
    ACC[3][0] = fmaf((A).w, (B).x, ACC[3][0]); \
    ACC[3][1] = fmaf((A).w, (B).y, ACC[3][1]); \
    ACC[3][2] = fmaf((A).w, (B).z, ACC[3][2]); \
    ACC[3][3] = fmaf((A).w, (B).w, ACC[3][3]); \
  } while (0)

// ---------------------------------------------------------------------------
// Wo f32 -> bf16
__global__ __launch_bounds__(256) void conv_wo(const float* __restrict__ W,
                                               short* __restrict__ Wb) {
  int i = (blockIdx.x * 256 + threadIdx.x) * 4;
  float4 v = *(const float4*)&W[i];
  *(short4v*)&Wb[i] = pack4bf(v.x, v.y, v.z, v.w);
}

// ---------------------------------------------------------------------------
// Per-head projection, f32 compute, bf16 row-major output [nh][L][64].
__global__ __launch_bounds__(256) void proj_qk(const float* __restrict__ x,
                                               const float* __restrict__ W,
                                               short* __restrict__ out) {
  __shared__ __align__(16) float wT[64 * 64];
  __shared__ __align__(16) float xT[64 * 64];
  const int t = threadIdx.x;
  const int w = t >> 6, lane = t & 63;
  const int nh = blockIdx.y;
  const int n = nh >> 4, h = nh & 15;
  const int l0 = blockIdx.x * 64;

  {
    const float* wrow = W + lane * 64 + w * 16;
#pragma unroll
    for (int i = 0; i < 4; ++i) {
      float4 v = *(const float4*)(wrow + i * 4);
      int e = w * 16 + i * 4;
      wT[(e + 0) * 64 + lane] = v.x;
      wT[(e + 1) * 64 + lane] = v.y;
      wT[(e + 2) * 64 + lane] = v.z;
      wT[(e + 3) * 64 + lane] = v.w;
    }
    const float* xrow =
        x + ((size_t)n * LSEQ + l0 + lane) * EMB + h * HD + w * 16;
#pragma unroll
    for (int i = 0; i < 4; ++i) {
      float4 v = *(const float4*)(xrow + i * 4);
      int e = w * 16 + i * 4;
      xT[(e + 0) * 64 + lane] = v.x;
      xT[(e + 1) * 64 + lane] = v.y;
      xT[(e + 2) * 64 + lane] = v.z;
      xT[(e + 3) * 64 + lane] = v.w;
    }
  }
  __syncthreads();

  const int c0 = (lane & 15) * 4;
  const int r0 = ((lane >> 4) & 3) * 4 + w * 16;
  float acc[4][4] = {};
#pragma unroll 8
  for (int e = 0; e < 64; ++e) {
    float4 xv = *(const float4*)&xT[e * 64 + r0];
    float4 wv = *(const float4*)&wT[e * 64 + c0];
    FMA16(acc, xv, wv);
  }

  short* ob = out + ((size_t)nh * LSEQ + l0) * HD;
#pragma unroll
  for (int i = 0; i < 4; ++i)
    *(short4v*)&ob[(size_t)(r0 + i) * HD + c0] =
        pack4bf(acc[i][0], acc[i][1], acc[i][2], acc[i][3]);
}

// Same projection but transposed bf16 output: Vt[nh][64 d][L].
__global__ __launch_bounds__(256) void proj_v(const float* __restrict__ x,
                                              const float* __restrict__ W,
                                              short* __restrict__ outT) {
  __shared__ __align__(16) float wT[64 * 64];
  __shared__ __align__(16) float xT[64 * 64];
  __shared__ __align__(16) short sT[64 * 68];  // [d][l], stride 68
  const int t = threadIdx.x;
  const int w = t >> 6, lane = t & 63;
  const int nh = blockIdx.y;
  const int n = nh >> 4, h = nh & 15;
  const int l0 = blockIdx.x * 64;

  {
    const float* wrow = W + lane * 64 + w * 16;
#pragma unroll
    for (int i = 0; i < 4; ++i) {
      float4 v = *(const float4*)(wrow + i * 4);
      int e = w * 16 + i * 4;
      wT[(e + 0) * 64 + lane] = v.x;
      wT[(e + 1) * 64 + lane] = v.y;
      wT[(e + 2) * 64 + lane] = v.z;
      wT[(e + 3) * 64 + lane] = v.w;
    }
    const float* xrow =
        x + ((size_t)n * LSEQ + l0 + lane) * EMB + h * HD + w * 16;
#pragma unroll
    for (int i = 0; i < 4; ++i) {
      float4 v = *(const float4*)(xrow + i * 4);
      int e = w * 16 + i * 4;
      xT[(e + 0) * 64 + lane] = v.x;
      xT[(e + 1) * 64 + lane] = v.y;
      xT[(e + 2) * 64 + lane] = v.z;
      xT[(e + 3) * 64 + lane] = v.w;
    }
  }
  __syncthreads();

  const int c0 = (lane & 15) * 4;
  const int r0 = ((lane >> 4) & 3) * 4 + w * 16;
  float acc[4][4] = {};
#pragma unroll 8
  for (int e = 0; e < 64; ++e) {
    float4 xv = *(const float4*)&xT[e * 64 + r0];
    float4 wv = *(const float4*)&wT[e * 64 + c0];
    FMA16(acc, xv, wv);
  }

  // transpose through LDS: sT[d][l] (d = c0+j, l = r0+i); i-values are in-lane.
#pragma unroll
  for (int j = 0; j < 4; ++j)
    *(short4v*)&sT[(c0 + j) * 68 + r0] =
        pack4bf(acc[0][j], acc[1][j], acc[2][j], acc[3][j]);
  __syncthreads();

  const int d = t >> 2, k4 = t & 3;
  union { short4v q[4]; short8 o[2]; } u;
#pragma unroll
  for (int i = 0; i < 4; ++i) u.q[i] = *(short4v*)&sT[d * 68 + k4 * 16 + i * 4];
  short* vb = outT + ((size_t)nh * HD + d) * LSEQ + l0 + k4 * 16;
  *(short8*)&vb[0] = u.o[0];
  *(short8*)&vb[8] = u.o[1];
}

// ---------------------------------------------------------------------------
// Flash attention with MFMA. Block = 4 waves, wave = 64 q-rows (block 256 q).
// Grid (LSEQ/256, N*H) = (8, 32).
__global__ __launch_bounds__(256, 1) void attn_kernel(
    const short* __restrict__ Qg,   // [nh][L][64] bf16
    const short* __restrict__ Kg,   // [nh][L][64] bf16
    const short* __restrict__ Vtg,  // [nh][64][L] bf16 (transposed)
    const int* __restrict__ mask,   // [N][L]
    short* __restrict__ AO)         // [N*L][E] bf16
{
  __shared__ __align__(16) short Ks[2][64 * 64];  // [k][d]
  __shared__ __align__(16) short Vs[2][64 * 64];  // [d][k] (V^T tile)
  __shared__ __align__(16) short Pl[4][64 * 72];  // per-wave P[q][k], stride 72
  __shared__ __align__(16) float Al[4][64];       // per-wave alpha / l

  const int t = threadIdx.x;
  const int wq = t >> 6, lane = t & 63;
  const int quad = lane >> 4, l15 = lane & 15;
  const int nh = blockIdx.y;
  const int n = nh >> 4, h = nh & 15;
  const int q0 = blockIdx.x * 256 + wq * 64;

  const float SCALE = 0.03125f;            // 1/sqrt(1024)
  const float MASKED = -1e20f * 0.03125f;  // matches reference where+scale

  // Resident Q B-fragments: B[d = c*32+quad*8+j][q = ntq*16+l15]
  short8 qf[4][2];
#pragma unroll
  for (int ntq = 0; ntq < 4; ++ntq)
#pragma unroll
    for (int c = 0; c < 2; ++c)
      qf[ntq][c] = *(const short8*)(Qg +
          ((size_t)nh * LSEQ + q0 + ntq * 16 + l15) * HD + c * 32 + quad * 8);

  // Staging helpers: 512 16B-slots per tile; thread handles slots t, 256+t.
  const int row0 = t >> 3, row1 = (256 + t) >> 3, ch = t & 7;
  short8 kr0, kr1, vr0, vr1;
  {
    const short* kb = Kg + ((size_t)nh * LSEQ + 0 * 64) * HD;
    kr0 = *(const short8*)(kb + (size_t)row0 * 64 + ch * 8);
    kr1 = *(const short8*)(kb + (size_t)row1 * 64 + ch * 8);
    const short* vb = Vtg + (size_t)nh * HD * LSEQ + 0 * 64;
    vr0 = *(const short8*)(vb + (size_t)row0 * LSEQ + ch * 8);
    vr1 = *(const short8*)(vb + (size_t)row1 * LSEQ + ch * 8);
  }
  *(short8*)&Ks[0][row0 * 64 + ch * 8] = kr0;
  *(short8*)&Ks[0][row1 * 64 + ch * 8] = kr1;
  *(short8*)&Vs[0][row0 * 64 + ch * 8] = vr0;
  *(short8*)&Vs[0][row1 * 64 + ch * 8] = vr1;
  __syncthreads();

  f32x4 O[4][4];  // [mq(q)][ntv(dv)]
#pragma unroll
  for (int a = 0; a < 4; ++a)
#pragma unroll
    for (int b = 0; b < 4; ++b) O[a][b] = (f32x4){0.f, 0.f, 0.f, 0.f};
  float m_i[4], l_i[4];
#pragma unroll
  for (int a = 0; a < 4; ++a) { m_i[a] = -3.4e38f; l_i[a] = 0.f; }

  for (int kt = 0; kt < LSEQ / 64; ++kt) {
    const int cur = kt & 1, nxt = cur ^ 1;
    // prefetch next K/V tile into registers
    if (kt < LSEQ / 64 - 1) {
      const short* kb = Kg + ((size_t)nh * LSEQ + (kt + 1) * 64) * HD;
      kr0 = *(const short8*)(kb + (size_t)row0 * 64 + ch * 8);
      kr1 = *(const short8*)(kb + (size_t)row1 * 64 + ch * 8);
      const short* vb = Vtg + (size_t)nh * HD * LSEQ + (kt + 1) * 64;
      vr0 = *(const short8*)(vb + (size_t)row0 * LSEQ + ch * 8);
      vr1 = *(const short8*)(vb + (size_t)row1 * LSEQ + ch * 8);
    }

    // ---- S^T = K·Q^T : St[mt(k)][ntq(q)]
    f32x4 St[4][4];
#pragma unroll
    for (int a = 0; a < 4; ++a)
#pragma unroll
      for (int b = 0; b < 4; ++b) St[a][b] = (f32x4){0.f, 0.f, 0.f, 0.f};
#pragma unroll
    for (int c = 0; c < 2; ++c) {
      short8 kf[4];
#pragma unroll
      for (int mt = 0; mt < 4; ++mt)
        kf[mt] = *(const short8*)&Ks[cur][(mt * 16 + l15) * 64 + c * 32 + quad * 8];
#pragma unroll
      for (int mt = 0; mt < 4; ++mt)
#pragma unroll
        for (int ntq = 0; ntq < 4; ++ntq)
          St[mt][ntq] = MFMA(kf[mt], qf[ntq][c], St[mt][ntq]);
    }

    // ---- mask + scale (k = row = kt*64 + mt*16 + quad*4 + r)
    const int* mrow = mask + n * LSEQ + kt * 64;
#pragma unroll
    for (int mt = 0; mt < 4; ++mt) {
      int4 mk = *(const int4*)&mrow[mt * 16 + quad * 4];
#pragma unroll
      for (int ntq = 0; ntq < 4; ++ntq) {
        St[mt][ntq][0] = mk.x ? St[mt][ntq][0] * SCALE : MASKED;
        St[mt][ntq][1] = mk.y ? St[mt][ntq][1] * SCALE : MASKED;
        St[mt][ntq][2] = mk.z ? St[mt][ntq][2] * SCALE : MASKED;
        St[mt][ntq][3] = mk.w ? St[mt][ntq][3] * SCALE : MASKED;
      }
    }

    // ---- online softmax per q-slot (q = ntq*16 + l15); p overwrites St
    float alpha_q[4];
#pragma unroll
    for (int ntq = 0; ntq < 4; ++ntq) {
      float rmx = -3.4e38f;
#pragma unroll
      for (int mt = 0; mt < 4; ++mt)
#pragma unroll
        for (int r = 0; r < 4; ++r) rmx = fmaxf(rmx, St[mt][ntq][r]);
      rmx = fmaxf(rmx, __shfl_xor(rmx, 16));
      rmx = fmaxf(rmx, __shfl_xor(rmx, 32));
      float mn = fmaxf(m_i[ntq], rmx);
      float a = __expf(m_i[ntq] - mn);
      m_i[ntq] = mn;
      float rs = 0.f;
#pragma unroll
      for (int mt = 0; mt < 4; ++mt)
#pragma unroll
        for (int r = 0; r < 4; ++r) {
          float p = __expf(St[mt][ntq][r] - mn);
          St[mt][ntq][r] = p;
          rs += p;
        }
      rs += __shfl_xor(rs, 16);
      rs += __shfl_xor(rs, 32);
      l_i[ntq] = l_i[ntq] * a + rs;
      alpha_q[ntq] = a;
    }

    // share alpha in C/D-row form via wave-private LDS
    if (lane < 16) {
#pragma unroll
      for (int ntq = 0; ntq < 4; ++ntq) Al[wq][ntq * 16 + lane] = alpha_q[ntq];
    }

    // ---- P (bf16) -> wave-private LDS tile Pl[q][k], packed b64 (k-adjacent)
#pragma unroll
    for (int ntq = 0; ntq < 4; ++ntq)
#pragma unroll
      for (int mt = 0; mt < 4; ++mt)
        *(short4v*)&Pl[wq][(ntq * 16 + l15) * 72 + mt * 16 + quad * 4] =
            pack4bf(St[mt][ntq][0], St[mt][ntq][1], St[mt][ntq][2],
                    St[mt][ntq][3]);

    // rescale O by alpha (row-indexed)
#pragma unroll
    for (int mq = 0; mq < 4; ++mq) {
      f32x4 ar = *(f32x4*)&Al[wq][mq * 16 + quad * 4];
#pragma unroll
      for (int ntv = 0; ntv < 4; ++ntv)
#pragma unroll
        for (int r = 0; r < 4; ++r) O[mq][ntv][r] *= ar[r];
    }

    // ---- PV: O[q][dv] += P[q][k] · V[k][dv]
#pragma unroll
    for (int c = 0; c < 2; ++c) {
      short8 pf[4];
#pragma unroll
      for (int mq = 0; mq < 4; ++mq)
        pf[mq] = *(const short8*)&Pl[wq][(mq * 16 + l15) * 72 + c * 32 + quad * 8];
#pragma unroll
      for (int ntv = 0; ntv < 4; ++ntv) {
        short8 vf =
            *(const short8*)&Vs[cur][(ntv * 16 + l15) * 64 + c * 32 + quad * 8];
#pragma unroll
        for (int mq = 0; mq < 4; ++mq) O[mq][ntv] = MFMA(pf[mq], vf, O[mq][ntv]);
      }
    }

    // write prefetched tile into the other buffer
    if (kt < LSEQ / 64 - 1) {
      *(short8*)&Ks[nxt][row0 * 64 + ch * 8] = kr0;
      *(short8*)&Ks[nxt][row1 * 64 + ch * 8] = kr1;
      *(short8*)&Vs[nxt][row0 * 64 + ch * 8] = vr0;
      *(short8*)&Vs[nxt][row1 * 64 + ch * 8] = vr1;
    }
    __syncthreads();
  }

  // ---- epilogue: divide by l, write bf16 AO[n*L + q][h*64 + dv]
  if (lane < 16) {
#pragma unroll
    for (int ntq = 0; ntq < 4; ++ntq) Al[wq][ntq * 16 + lane] = l_i[ntq];
  }
  short* ob = AO + ((size_t)n * LSEQ + q0) * EMB + h * HD;
#pragma unroll
  for (int mq = 0; mq < 4; ++mq) {
    f32x4 lr = *(f32x4*)&Al[wq][mq * 16 + quad * 4];
    f32x4 inv;
#pragma unroll
    for (int r = 0; r < 4; ++r) inv[r] = 1.f / lr[r];
#pragma unroll
    for (int ntv = 0; ntv < 4; ++ntv)
#pragma unroll
      for (int r = 0; r < 4; ++r)
        ob[(size_t)(mq * 16 + quad * 4 + r) * EMB + ntv * 16 + l15] =
            bf16of(O[mq][ntv][r] * inv[r]);
  }
}

// ---------------------------------------------------------------------------
// Out-projection: C[r][j] = sum_e A[r][e]*Wo[j][e] + bo[j], bf16 MFMA.
// 128x128 tile per block; 4 waves 2x2; BK=64; double-buffered LDS.
__global__ __launch_bounds__(256, 1) void outproj_mfma(
    const short* __restrict__ A,   // [N*L][E] bf16
    const short* __restrict__ W,   // [E][E] bf16 (Wo[j][e])
    const float* __restrict__ bo,  // [E]
    float* __restrict__ C)         // [N*L][E]
{
  __shared__ __align__(16) short As[2][128 * 64];
  __shared__ __align__(16) short Bs[2][128 * 64];
  const int t = threadIdx.x;
  const int wq = t >> 6, lane = t & 63;
  const int quad = lane >> 4, l15 = lane & 15;
  const int wr = wq >> 1, wc = wq & 1;
  const int j0 = blockIdx.x * 128, r0 = blockIdx.y * 128;

  f32x4 acc[4][4];
#pragma unroll
  for (int a = 0; a < 4; ++a)
#pragma unroll
    for (int b = 0; b < 4; ++b) acc[a][b] = (f32x4){0.f, 0.f, 0.f, 0.f};

  // 1024 16B-slots per tile; thread handles slots t+i*256 (i<4).
  short8 ar[4], br[4];
#pragma unroll
  for (int i = 0; i < 4; ++i) {
    int slot = i * 256 + t, row = slot >> 3, ch = slot & 7;
    ar[i] = *(const short8*)(A + (size_t)(r0 + row) * EMB + ch * 8);
    br[i] = *(const short8*)(W + (size_t)(j0 + row) * EMB + ch * 8);
  }
#pragma unroll
  for (int i = 0; i < 4; ++i) {
    int slot = i * 256 + t;
    *(short8*)&As[0][slot * 8] = ar[i];
    *(short8*)&Bs[0][slot * 8] = br[i];
  }
  __syncthreads();

  for (int ek = 0; ek < EMB; ek += 64) {
    const int cur = (ek >> 6) & 1, nxt = cur ^ 1;
    if (ek + 64 < EMB) {
#pragma unroll
      for (int i = 0; i < 4; ++i) {
        int slot = i * 256 + t, row = slot >> 3, ch = slot & 7;
        ar[i] = *(const short8*)(A + (size_t)(r0 + row) * EMB + ek + 64 + ch * 8);
        br[i] = *(const short8*)(W + (size_t)(j0 + row) * EMB + ek + 64 + ch * 8);
      }
    }
#pragma unroll
    for (int c = 0; c < 2; ++c) {
      short8 af[4], bfr[4];
#pragma unroll
      for (int mt = 0; mt < 4; ++mt)
        af[mt] = *(const short8*)&As[cur][(wr * 64 + mt * 16 + l15) * 64 +
                                          c * 32 + quad * 8];
#pragma unroll
      for (int nt = 0; nt < 4; ++nt)
        bfr[nt] = *(const short8*)&Bs[cur][(wc * 64 + nt * 16 + l15) * 64 +
                                           c * 32 + quad * 8];
#pragma unroll
      for (int mt = 0; mt < 4; ++mt)
#pragma unroll
        for (int nt = 0; nt < 4; ++nt)
          acc[mt][nt] = MFMA(af[mt], bfr[nt], acc[mt][nt]);
    }
    if (ek + 64 < EMB) {
#pragma unroll
      for (int i = 0; i < 4; ++i) {
        int slot = i * 256 + t;
        *(short8*)&As[nxt][slot * 8] = ar[i];
        *(short8*)&Bs[nxt][slot * 8] = br[i];
      }
    }
    __syncthreads();
  }

  float bn[4];
#pragma unroll
  for (int nt = 0; nt < 4; ++nt) bn[nt] = bo[j0 + wc * 64 + nt * 16 + l15];
#pragma unroll
  for (int mt = 0; mt < 4; ++mt)
#pragma unroll
    for (int nt = 0; nt < 4; ++nt)
#pragma unroll
      for (int r = 0; r < 4; ++r)
        C[(size_t)(r0 + wr * 64 + mt * 16 + quad * 4 + r) * EMB + j0 + wc * 64 +
          nt * 16 + l15] = acc[mt][nt][r] + bn[nt];
}

// ---------------------------------------------------------------------------
extern "C" void kernel_launch(void* const* d_in, const int* in_sizes, int n_in,
                              void* d_out, int out_size, void* d_ws,
                              size_t ws_size, hipStream_t stream) {
  const float* values = (const float*)d_in[0];
  const float* keys   = (const float*)d_in[1];
  const float* query  = (const float*)d_in[2];
  const int*   mask   = (const int*)d_in[3];
  const float* Wv     = (const float*)d_in[4];
  const float* Wk     = (const float*)d_in[5];
  const float* Wq     = (const float*)d_in[6];
  const float* Wo     = (const float*)d_in[7];
  const float* bo     = (const float*)d_in[8];
  float* out = (float*)d_out;

  short* ws = (short*)d_ws;
  const size_t tsz = (size_t)NB * NHEADS * LSEQ * HD;  // 4 Mi shorts
  short* Qb  = ws;
  short* Kb  = Qb + tsz;
  short* Vt  = Kb + tsz;
  short* AOb = Vt + tsz;
  short* Wb  = AOb + tsz;  // 1 Mi shorts; total ~36 MB of d_ws

  dim3 blk(256);
  conv_wo<<<dim3(EMB * EMB / 1024), blk, 0, stream>>>(Wo, Wb);
  proj_qk<<<dim3(LSEQ / 64, NB * NHEADS), blk, 0, stream>>>(query, Wq, Qb);
  proj_qk<<<dim3(LSEQ / 64, NB * NHEADS), blk, 0, stream>>>(keys, Wk, Kb);
  proj_v<<<dim3(LSEQ / 64, NB * NHEADS), blk, 0, stream>>>(values, Wv, Vt);
  attn_kernel<<<dim3(LSEQ / 256, NB * NHEADS), blk, 0, stream>>>(Qb, Kb, Vt,
                                                                 mask, AOb);
  outproj_mfma<<<dim3(EMB / 128, NB * LSEQ / 128), blk, 0, stream>>>(AOb, Wb,
                                                                     bo, out);
}

// Round 3
// 202.710 us; speedup vs baseline: 4.1918x; 1.2749x over previous
//
#include <hip/hip_runtime.h>
#include <hip/hip_bf16.h>
#include <cstdint>

// MultiHeadSelfAttention N=2,L=2048,E=1024,H=16,D=64.
// Round 3: attn restructured — no-max softmax (exp2-domain, scale*log2e folded
// into Q), mask as C-init bias, l via ones-column MFMA, XOR-swizzled K/V LDS
// (conflict-free), 32q/wave -> 512 blocks (2 blocks/CU, 2 waves/SIMD).
// Projections fused into one launch (z = q/k/v).

#define NB 2
#define LSEQ 2048
#define EMB 1024
#define NHEADS 16
#define HD 64

// (1/sqrt(1024)) * log2(e): folded into Q so P = exp2(S + bias)
#define QSCALE 0.045084220027780106f
#define MASKBIAS -1e30f

using short8 = __attribute__((ext_vector_type(8))) short;
using short4v = __attribute__((ext_vector_type(4))) short;
using f32x4 = __attribute__((ext_vector_type(4))) float;

__device__ inline short bf16of(float f) {
  union { __hip_bfloat16 b; short s; } u;
  u.b = __float2bfloat16(f);
  return u.s;
}

__device__ inline short4v pack4bf(float a, float b, float c, float d) {
  union { __hip_bfloat162 v[2]; short4v s; } u;
  u.v[0] = __float22bfloat162_rn(make_float2(a, b));
  u.v[1] = __float22bfloat162_rn(make_float2(c, d));
  return u.s;
}

__device__ inline float fexp2(float x) {
#if __has_builtin(__builtin_amdgcn_exp2f)
  return __builtin_amdgcn_exp2f(x);
#else
  return exp2f(x);
#endif
}

#define MFMA(A, B, C) __builtin_amdgcn_mfma_f32_16x16x32_bf16((A), (B), (C), 0, 0, 0)

#define FMA16(ACC, A, B)                       \
  do {                                         \
    ACC[0][0] = fmaf((A).x, (B).x, ACC[0][0]); \
    ACC[0][1] = fmaf((A).x, (B).y, ACC[0][1]); \
    ACC[0][2] = fmaf((A).x, (B).z, ACC[0][2]); \
    ACC[0][3] = fmaf((A).x, (B).w, ACC[0][3]); \
    ACC[1][0] = fmaf((A).y, (B).x, ACC[1][0]); \
    ACC[1][1] = fmaf((A).y, (B).y, ACC[1][1]); \
    ACC[1][2] = fmaf((A).y, (B).z, ACC[1][2]); \
    ACC[1][3] = fmaf((A).y, (B).w, ACC[1][3]); \
    ACC[2][0] = fmaf((A).z, (B).x, ACC[2][0]); \
    ACC[2][1] = fmaf((A).z, (B).y, ACC[2][1]); \
    ACC[2][2] = fmaf((A).z, (B).z, ACC[2][2]); \
    ACC[2][3] = fmaf((A).z, (B).w, ACC[2][3]); \
    ACC[3][0] = fmaf((A).w, (B).x, ACC[3][0]); \
    ACC[3][1] = fmaf((A).w, (B).y, ACC[3][1]); \
    ACC[3][2] = fmaf((A).w, (B).z, ACC[3][2]); \
    ACC[3][3] = fmaf((A).w, (B).w, ACC[3][3]); \
  } while (0)

// ---------------------------------------------------------------------------
// Wo f32->bf16 + mask -> bias float (exp2-domain: 0 or -1e30).
__global__ __launch_bounds__(256) void conv_wo_bias(const float* __restrict__ W,
                                                    const int* __restrict__ mask,
                                                    short* __restrict__ Wb,
                                                    float* __restrict__ biasf) {
  int i = (blockIdx.x * 256 + threadIdx.x) * 4;
  float4 v = *(const float4*)&W[i];
  *(short4v*)&Wb[i] = pack4bf(v.x, v.y, v.z, v.w);
  if (i < NB * LSEQ) {
    int4 m = *(const int4*)&mask[i];
    float4 b;
    b.x = m.x ? 0.f : MASKBIAS;
    b.y = m.y ? 0.f : MASKBIAS;
    b.z = m.z ? 0.f : MASKBIAS;
    b.w = m.w ? 0.f : MASKBIAS;
    *(float4*)&biasf[i] = b;
  }
}

// ---------------------------------------------------------------------------
// Fused per-head projections. z=0: Q (scaled by QSCALE, row-major out),
// z=1: K (row-major out), z=2: V (transposed out Vt[nh][d][L]).
__global__ __launch_bounds__(256) void proj_fused(
    const float* __restrict__ xq, const float* __restrict__ xk,
    const float* __restrict__ xv, const float* __restrict__ Wq,
    const float* __restrict__ Wk, const float* __restrict__ Wv,
    short* __restrict__ Qb, short* __restrict__ Kb, short* __restrict__ Vt) {
  __shared__ __align__(16) float wT[64 * 64];
  __shared__ __align__(16) float xT[64 * 64];
  __shared__ __align__(16) short sT[64 * 68];  // V transpose staging
  const int z = blockIdx.z;
  const float* x = (z == 0) ? xq : (z == 1) ? xk : xv;
  const float* W = (z == 0) ? Wq : (z == 1) ? Wk : Wv;
  const float sc = (z == 0) ? QSCALE : 1.0f;
  const int t = threadIdx.x;
  const int w = t >> 6, lane = t & 63;
  const int nh = blockIdx.y;
  const int n = nh >> 4, h = nh & 15;
  const int l0 = blockIdx.x * 64;

  {
    const float* wrow = W + lane * 64 + w * 16;
#pragma unroll
    for (int i = 0; i < 4; ++i) {
      float4 v = *(const float4*)(wrow + i * 4);
      int e = w * 16 + i * 4;
      wT[(e + 0) * 64 + lane] = v.x;
      wT[(e + 1) * 64 + lane] = v.y;
      wT[(e + 2) * 64 + lane] = v.z;
      wT[(e + 3) * 64 + lane] = v.w;
    }
    const float* xrow =
        x + ((size_t)n * LSEQ + l0 + lane) * EMB + h * HD + w * 16;
#pragma unroll
    for (int i = 0; i < 4; ++i) {
      float4 v = *(const float4*)(xrow + i * 4);
      int e = w * 16 + i * 4;
      xT[(e + 0) * 64 + lane] = v.x;
      xT[(e + 1) * 64 + lane] = v.y;
      xT[(e + 2) * 64 + lane] = v.z;
      xT[(e + 3) * 64 + lane] = v.w;
    }
  }
  __syncthreads();

  const int c0 = (lane & 15) * 4;
  const int r0 = ((lane >> 4) & 3) * 4 + w * 16;
  float acc[4][4] = {};
#pragma unroll 8
  for (int e = 0; e < 64; ++e) {
    float4 xv4 = *(const float4*)&xT[e * 64 + r0];
    float4 wv4 = *(const float4*)&wT[e * 64 + c0];
    FMA16(acc, xv4, wv4);
  }
#pragma unroll
  for (int i = 0; i < 4; ++i)
#pragma unroll
    for (int j = 0; j < 4; ++j) acc[i][j] *= sc;

  if (z != 2) {
    short* out = (z == 0) ? Qb : Kb;
    short* ob = out + ((size_t)nh * LSEQ + l0) * HD;
#pragma unroll
    for (int i = 0; i < 4; ++i)
      *(short4v*)&ob[(size_t)(r0 + i) * HD + c0] =
          pack4bf(acc[i][0], acc[i][1], acc[i][2], acc[i][3]);
  } else {
    // transpose via LDS: sT[d][l]
#pragma unroll
    for (int j = 0; j < 4; ++j)
      *(short4v*)&sT[(c0 + j) * 68 + r0] =
          pack4bf(acc[0][j], acc[1][j], acc[2][j], acc[3][j]);
    __syncthreads();
    const int d = t >> 2, k4 = t & 3;
    union { short4v q[4]; short8 o[2]; } u;
#pragma unroll
    for (int i = 0; i < 4; ++i)
      u.q[i] = *(short4v*)&sT[d * 68 + k4 * 16 + i * 4];
    short* vb = Vt + ((size_t)nh * HD + d) * LSEQ + l0 + k4 * 16;
    *(short8*)&vb[0] = u.o[0];
    *(short8*)&vb[8] = u.o[1];
  }
}

// ---------------------------------------------------------------------------
// Flash attention, no-max softmax. Wave = 32 q; block = 4 waves = 128 q.
// Grid (LSEQ/128, N*H) = (16, 32) = 512 blocks -> 2 blocks/CU, 8 waves/CU.
// K/V tiles XOR-swizzled in LDS (conflict-free); P via stride-72 wave-private
// LDS; l accumulated by ones-column MFMA; mask enters as C-init bias.
__global__ __launch_bounds__(256, 2) void attn_kernel(
    const short* __restrict__ Qg,    // [nh][L][64] bf16, pre-scaled
    const short* __restrict__ Kg,    // [nh][L][64] bf16
    const short* __restrict__ Vtg,   // [nh][64][L] bf16 (transposed)
    const float* __restrict__ biasf, // [N][L]: 0 or -1e30
    short* __restrict__ AO)          // [N*L][E] bf16
{
  __shared__ __align__(16) short Ks[2][64 * 64];
  __shared__ __align__(16) short Vs[2][64 * 64];
  __shared__ __align__(16) short Pl[4][32 * 72];

  const int t = threadIdx.x;
  const int wq = t >> 6, lane = t & 63;
  const int quad = lane >> 4, l15 = lane & 15;
  const int nh = blockIdx.y;
  const int n = nh >> 4, h = nh & 15;
  const int q0 = blockIdx.x * 128 + wq * 32;

  // Resident Q B-fragments: B[d = c*32+quad*8+j][q = ntq*16+l15]
  short8 qf[2][2];
#pragma unroll
  for (int ntq = 0; ntq < 2; ++ntq)
#pragma unroll
    for (int c = 0; c < 2; ++c)
      qf[ntq][c] = *(const short8*)(Qg +
          ((size_t)nh * LSEQ + q0 + ntq * 16 + l15) * HD + c * 32 + quad * 8);

  // Staging: 512 16B slots/tile; thread handles slots t and t+256.
  const int rowA = t >> 3, chA = t & 7;
  const int rowB = rowA + 32;
  const int ldsA = rowA * 64 + ((chA ^ (rowA & 7)) * 8);  // swizzled
  const int ldsB = rowB * 64 + ((chA ^ (rowB & 7)) * 8);
  const short* kbase = Kg + (size_t)nh * LSEQ * HD;
  const short* vbase = Vtg + (size_t)nh * HD * LSEQ;

  short8 kr0 = *(const short8*)(kbase + (size_t)rowA * HD + chA * 8);
  short8 kr1 = *(const short8*)(kbase + (size_t)rowB * HD + chA * 8);
  short8 vr0 = *(const short8*)(vbase + (size_t)rowA * LSEQ + chA * 8);
  short8 vr1 = *(const short8*)(vbase + (size_t)rowB * LSEQ + chA * 8);
  *(short8*)&Ks[0][ldsA] = kr0;
  *(short8*)&Ks[0][ldsB] = kr1;
  *(short8*)&Vs[0][ldsA] = vr0;
  *(short8*)&Vs[0][ldsB] = vr1;
  __syncthreads();

  f32x4 O[2][4], Ol[2];
#pragma unroll
  for (int a = 0; a < 2; ++a) {
    Ol[a] = (f32x4){0.f, 0.f, 0.f, 0.f};
#pragma unroll
    for (int b = 0; b < 4; ++b) O[a][b] = (f32x4){0.f, 0.f, 0.f, 0.f};
  }
  const short one_bf = (short)0x3F80;  // bf16 1.0
  const short8 ones = {one_bf, one_bf, one_bf, one_bf,
                       one_bf, one_bf, one_bf, one_bf};

  // swizzled fragment-read column offsets (row&7 == l15&7)
  const int sw0 = ((0 * 4 + quad) ^ (l15 & 7)) * 8;
  const int sw1 = ((1 * 4 + quad) ^ (l15 & 7)) * 8;
  const float* bbase = biasf + n * LSEQ;

  for (int kt = 0; kt < LSEQ / 64; ++kt) {
    const int cur = kt & 1, nxt = cur ^ 1;
    if (kt < LSEQ / 64 - 1) {
      const short* kb = kbase + (size_t)((kt + 1) * 64) * HD;
      kr0 = *(const short8*)(kb + (size_t)rowA * HD + chA * 8);
      kr1 = *(const short8*)(kb + (size_t)rowB * HD + chA * 8);
      const short* vb = vbase + (kt + 1) * 64;
      vr0 = *(const short8*)(vb + (size_t)rowA * LSEQ + chA * 8);
      vr1 = *(const short8*)(vb + (size_t)rowB * LSEQ + chA * 8);
    }

    // ---- S^T (+mask bias): St[mt(k)][ntq(q)], C-init = bias
    f32x4 St[4][2];
#pragma unroll
    for (int mt = 0; mt < 4; ++mt) {
      f32x4 bv = *(const f32x4*)(bbase + kt * 64 + mt * 16 + quad * 4);
      St[mt][0] = bv;
      St[mt][1] = bv;
    }
#pragma unroll
    for (int c = 0; c < 2; ++c) {
      const int sw = c ? sw1 : sw0;
      short8 kf[4];
#pragma unroll
      for (int mt = 0; mt < 4; ++mt)
        kf[mt] = *(const short8*)&Ks[cur][(mt * 16 + l15) * 64 + sw];
#pragma unroll
      for (int mt = 0; mt < 4; ++mt)
#pragma unroll
        for (int ntq = 0; ntq < 2; ++ntq)
          St[mt][ntq] = MFMA(kf[mt], qf[ntq][c], St[mt][ntq]);
    }

    // ---- P = exp2(St) (no max subtraction: logits are O(1))
#pragma unroll
    for (int mt = 0; mt < 4; ++mt)
#pragma unroll
      for (int ntq = 0; ntq < 2; ++ntq)
#pragma unroll
        for (int r = 0; r < 4; ++r)
          St[mt][ntq][r] = fexp2(St[mt][ntq][r]);

    // ---- pack P -> wave-private LDS tile Pl[q][k] (stride 72, b64 writes)
#pragma unroll
    for (int ntq = 0; ntq < 2; ++ntq)
#pragma unroll
      for (int mt = 0; mt < 4; ++mt)
        *(short4v*)&Pl[wq][(ntq * 16 + l15) * 72 + mt * 16 + quad * 4] =
            pack4bf(St[mt][ntq][0], St[mt][ntq][1], St[mt][ntq][2],
                    St[mt][ntq][3]);

    // ---- PV + l: O[q][dv] += P·V, Ol += P·1
#pragma unroll
    for (int c = 0; c < 2; ++c) {
      const int sw = c ? sw1 : sw0;
      short8 pf[2];
#pragma unroll
      for (int mq = 0; mq < 2; ++mq)
        pf[mq] = *(const short8*)&Pl[wq][(mq * 16 + l15) * 72 + c * 32 + quad * 8];
#pragma unroll
      for (int ntv = 0; ntv < 4; ++ntv) {
        short8 vf = *(const short8*)&Vs[cur][(ntv * 16 + l15) * 64 + sw];
#pragma unroll
        for (int mq = 0; mq < 2; ++mq) O[mq][ntv] = MFMA(pf[mq], vf, O[mq][ntv]);
      }
#pragma unroll
      for (int mq = 0; mq < 2; ++mq) Ol[mq] = MFMA(pf[mq], ones, Ol[mq]);
    }

    if (kt < LSEQ / 64 - 1) {
      *(short8*)&Ks[nxt][ldsA] = kr0;
      *(short8*)&Ks[nxt][ldsB] = kr1;
      *(short8*)&Vs[nxt][ldsA] = vr0;
      *(short8*)&Vs[nxt][ldsB] = vr1;
    }
    __syncthreads();
  }

  // ---- epilogue: O/l -> bf16 AO[n*L + q][h*64 + dv]
  short* ob = AO + ((size_t)n * LSEQ + q0) * EMB + h * HD;
#pragma unroll
  for (int mq = 0; mq < 2; ++mq) {
    f32x4 inv;
#pragma unroll
    for (int r = 0; r < 4; ++r) inv[r] = 1.f / Ol[mq][r];
#pragma unroll
    for (int ntv = 0; ntv < 4; ++ntv)
#pragma unroll
      for (int r = 0; r < 4; ++r)
        ob[(size_t)(mq * 16 + quad * 4 + r) * EMB + ntv * 16 + l15] =
            bf16of(O[mq][ntv][r] * inv[r]);
  }
}

// ---------------------------------------------------------------------------
// Out-projection: C[r][j] = sum_e A[r][e]*Wo[j][e] + bo[j], bf16 MFMA,
// 128x128 tile, double-buffered LDS (round-2 verified).
__global__ __launch_bounds__(256, 1) void outproj_mfma(
    const short* __restrict__ A, const short* __restrict__ W,
    const float* __restrict__ bo, float* __restrict__ C) {
  __shared__ __align__(16) short As[2][128 * 64];
  __shared__ __align__(16) short Bs[2][128 * 64];
  const int t = threadIdx.x;
  const int wq = t >> 6, lane = t & 63;
  const int quad = lane >> 4, l15 = lane & 15;
  const int wr = wq >> 1, wc = wq & 1;
  const int j0 = blockIdx.x * 128, r0 = blockIdx.y * 128;

  f32x4 acc[4][4];
#pragma unroll
  for (int a = 0; a < 4; ++a)
#pragma unroll
    for (int b = 0; b < 4; ++b) acc[a][b] = (f32x4){0.f, 0.f, 0.f, 0.f};

  short8 ar[4], br[4];
#pragma unroll
  for (int i = 0; i < 4; ++i) {
    int slot = i * 256 + t, row = slot >> 3, ch = slot & 7;
    ar[i] = *(const short8*)(A + (size_t)(r0 + row) * EMB + ch * 8);
    br[i] = *(const short8*)(W + (size_t)(j0 + row) * EMB + ch * 8);
  }
#pragma unroll
  for (int i = 0; i < 4; ++i) {
    int slot = i * 256 + t;
    *(short8*)&As[0][slot * 8] = ar[i];
    *(short8*)&Bs[0][slot * 8] = br[i];
  }
  __syncthreads();

  for (int ek = 0; ek < EMB; ek += 64) {
    const int cur = (ek >> 6) & 1, nxt = cur ^ 1;
    if (ek + 64 < EMB) {
#pragma unroll
      for (int i = 0; i < 4; ++i) {
        int slot = i * 256 + t, row = slot >> 3, ch = slot & 7;
        ar[i] = *(const short8*)(A + (size_t)(r0 + row) * EMB + ek + 64 + ch * 8);
        br[i] = *(const short8*)(W + (size_t)(j0 + row) * EMB + ek + 64 + ch * 8);
      }
    }
#pragma unroll
    for (int c = 0; c < 2; ++c) {
      short8 af[4], bfr[4];
#pragma unroll
      for (int mt = 0; mt < 4; ++mt)
        af[mt] = *(const short8*)&As[cur][(wr * 64 + mt * 16 + l15) * 64 +
                                          c * 32 + quad * 8];
#pragma unroll
      for (int nt = 0; nt < 4; ++nt)
        bfr[nt] = *(const short8*)&Bs[cur][(wc * 64 + nt * 16 + l15) * 64 +
                                           c * 32 + quad * 8];
#pragma unroll
      for (int mt = 0; mt < 4; ++mt)
#pragma unroll
        for (int nt = 0; nt < 4; ++nt)
          acc[mt][nt] = MFMA(af[mt], bfr[nt], acc[mt][nt]);
    }
    if (ek + 64 < EMB) {
#pragma unroll
      for (int i = 0; i < 4; ++i) {
        int slot = i * 256 + t;
        *(short8*)&As[nxt][slot * 8] = ar[i];
        *(short8*)&Bs[nxt][slot * 8] = br[i];
      }
    }
    __syncthreads();
  }

  float bn[4];
#pragma unroll
  for (int nt = 0; nt < 4; ++nt) bn[nt] = bo[j0 + wc * 64 + nt * 16 + l15];
#pragma unroll
  for (int mt = 0; mt < 4; ++mt)
#pragma unroll
    for (int nt = 0; nt < 4; ++nt)
#pragma unroll
      for (int r = 0; r < 4; ++r)
        C[(size_t)(r0 + wr * 64 + mt * 16 + quad * 4 + r) * EMB + j0 + wc * 64 +
          nt * 16 + l15] = acc[mt][nt][r] + bn[nt];
}

// ---------------------------------------------------------------------------
extern "C" void kernel_launch(void* const* d_in, const int* in_sizes, int n_in,
                              void* d_out, int out_size, void* d_ws,
                              size_t ws_size, hipStream_t stream) {
  const float* values = (const float*)d_in[0];
  const float* keys   = (const float*)d_in[1];
  const float* query  = (const float*)d_in[2];
  const int*   mask   = (const int*)d_in[3];
  const float* Wv     = (const float*)d_in[4];
  const float* Wk     = (const float*)d_in[5];
  const float* Wq     = (const float*)d_in[6];
  const float* Wo     = (const float*)d_in[7];
  const float* bo     = (const float*)d_in[8];
  float* out = (float*)d_out;

  short* ws = (short*)d_ws;
  const size_t tsz = (size_t)NB * NHEADS * LSEQ * HD;  // 4 Mi shorts
  short* Qb  = ws;
  short* Kb  = Qb + tsz;
  short* Vt  = Kb + tsz;
  short* AOb = Vt + tsz;
  short* Wb  = AOb + tsz;          // 1 Mi shorts
  float* biasf = (float*)(Wb + (size_t)EMB * EMB);  // N*L floats

  dim3 blk(256);
  conv_wo_bias<<<dim3(EMB * EMB / 1024), blk, 0, stream>>>(Wo, mask, Wb, biasf);
  proj_fused<<<dim3(LSEQ / 64, NB * NHEADS, 3), blk, 0, stream>>>(
      query, keys, values, Wq, Wk, Wv, Qb, Kb, Vt);
  attn_kernel<<<dim3(LSEQ / 128, NB * NHEADS), blk, 0, stream>>>(Qb, Kb, Vt,
                                                                 biasf, AOb);
  outproj_mfma<<<dim3(EMB / 128, NB * LSEQ / 128), blk, 0, stream>>>(AOb, Wb,
                                                                     bo, out);
}

// Round 4
// 188.013 us; speedup vs baseline: 4.5195x; 1.0782x over previous
//
#include <hip/hip_runtime.h>
#include <hip/hip_bf16.h>
#include <cstdint>

// MultiHeadSelfAttention N=2,L=2048,E=1024,H=16,D=64.
// Round 4: (a) attn: 16q/wave, 64q/block, grid 1024 -> 4 blocks/CU (16
// waves/CU), single-buffered XOR-swizzled K/V LDS; (b) projections as
// LDS-free MFMA reading A/B frags straight from global (Q/K via C=W*x^T,
// V via C=x*W^T -> V^T directly); (c) outproj 128x64 tiles, grid 512,
// swizzled LDS. Mask as C-init bias, l via ones-MFMA (round-3 verified).

#define NB 2
#define LSEQ 2048
#define EMB 1024
#define NHEADS 16
#define HD 64

// (1/sqrt(1024)) * log2(e): folded into Wq bf16 conversion; P = exp2(S+bias)
#define QSCALE 0.045084220027780106f
#define MASKBIAS -1e30f

using short8 = __attribute__((ext_vector_type(8))) short;
using short4v = __attribute__((ext_vector_type(4))) short;
using f32x4 = __attribute__((ext_vector_type(4))) float;

__device__ inline short bf16of(float f) {
  union { __hip_bfloat16 b; short s; } u;
  u.b = __float2bfloat16(f);
  return u.s;
}

__device__ inline short4v pack4bf(float a, float b, float c, float d) {
  union { __hip_bfloat162 v[2]; short4v s; } u;
  u.v[0] = __float22bfloat162_rn(make_float2(a, b));
  u.v[1] = __float22bfloat162_rn(make_float2(c, d));
  return u.s;
}

__device__ inline short8 pack8bf(float4 a, float4 b) {
  union { short4v q[2]; short8 o; } u;
  u.q[0] = pack4bf(a.x, a.y, a.z, a.w);
  u.q[1] = pack4bf(b.x, b.y, b.z, b.w);
  return u.o;
}

__device__ inline float fexp2(float x) {
#if __has_builtin(__builtin_amdgcn_exp2f)
  return __builtin_amdgcn_exp2f(x);
#else
  return exp2f(x);
#endif
}

#define MFMA(A, B, C) __builtin_amdgcn_mfma_f32_16x16x32_bf16((A), (B), (C), 0, 0, 0)

// ---------------------------------------------------------------------------
// Convert Wo->bf16 (grid-wide), Wq(*QSCALE)/Wk/Wv->bf16 (blocks 0-2),
// mask->bias float (blocks 4-7).
__global__ __launch_bounds__(256) void conv_kernel(
    const float* __restrict__ Wq, const float* __restrict__ Wk,
    const float* __restrict__ Wv, const float* __restrict__ Wo,
    const int* __restrict__ mask, short* __restrict__ Wqb,
    short* __restrict__ Wkb, short* __restrict__ Wvb,
    short* __restrict__ Wob, float* __restrict__ biasf) {
  const int b = blockIdx.x, t = threadIdx.x;
  {
    int i = (b * 256 + t) * 4;  // 1024 blocks * 1024 = 1Mi elements of Wo
    float4 v = *(const float4*)&Wo[i];
    *(short4v*)&Wob[i] = pack4bf(v.x, v.y, v.z, v.w);
  }
  if (b < 3) {
    const float* src = (b == 0) ? Wq : (b == 1) ? Wk : Wv;
    short* dst = (b == 0) ? Wqb : (b == 1) ? Wkb : Wvb;
    const float sc = (b == 0) ? QSCALE : 1.0f;
#pragma unroll
    for (int i = 0; i < 4; ++i) {
      int j = t * 16 + i * 4;  // 256*16 = 4096
      float4 v = *(const float4*)&src[j];
      *(short4v*)&dst[j] = pack4bf(v.x * sc, v.y * sc, v.z * sc, v.w * sc);
    }
  } else if (b >= 4 && b < 8) {
    int i = ((b - 4) * 256 + t) * 4;  // 4096 mask ints
    int4 m = *(const int4*)&mask[i];
    float4 o;
    o.x = m.x ? 0.f : MASKBIAS;
    o.y = m.y ? 0.f : MASKBIAS;
    o.z = m.z ? 0.f : MASKBIAS;
    o.w = m.w ? 0.f : MASKBIAS;
    *(float4*)&biasf[i] = o;
  }
}

// ---------------------------------------------------------------------------
// LDS-free MFMA projections. Block = 4 waves, 64 l-rows, one (n,h,z).
// z<2 (Q,K): C = W * x^T (M=d, N=l) -> C cols = l (lane l15), rows = d ->
//   short4v stores into row-major [l][d].
// z==2 (V): C = x * W^T (M=l, N=d) -> C cols = d, rows = l -> short4v
//   stores into V^T [d][L].
// All A/B fragments are contiguous short8 (or float4-pair) global reads.
__global__ __launch_bounds__(256) void proj_mfma(
    const float* __restrict__ xq, const float* __restrict__ xk,
    const float* __restrict__ xv, const short* __restrict__ Wqb,
    const short* __restrict__ Wkb, const short* __restrict__ Wvb,
    short* __restrict__ Qb, short* __restrict__ Kb, short* __restrict__ Vt) {
  const int t = threadIdx.x;
  const int wq = t >> 6, lane = t & 63;
  const int quad = lane >> 4, l15 = lane & 15;
  const int z = blockIdx.z, nh = blockIdx.y;
  const int n = nh >> 4, h = nh & 15;
  const int l0 = blockIdx.x * 64;
  const float* x = (z == 0) ? xq : (z == 1) ? xk : xv;
  const short* W = (z == 0) ? Wqb : (z == 1) ? Wkb : Wvb;
  const int lrow = l0 + wq * 16 + l15;  // this lane's l (n-index for z<2)

  // x fragment: 8 f32 -> bf16, k = e chunk c*32+quad*8
  short8 xf[2];
  const float* xr = x + ((size_t)n * LSEQ + lrow) * EMB + h * HD;
#pragma unroll
  for (int c = 0; c < 2; ++c) {
    float4 a = *(const float4*)(xr + c * 32 + quad * 8);
    float4 b = *(const float4*)(xr + c * 32 + quad * 8 + 4);
    xf[c] = pack8bf(a, b);
  }
  // W fragments: row (mt*16+l15) of W[d][e] (A for z<2; B=W^T for z==2)
  short8 wf[4][2];
#pragma unroll
  for (int mt = 0; mt < 4; ++mt)
#pragma unroll
    for (int c = 0; c < 2; ++c)
      wf[mt][c] = *(const short8*)(W + (mt * 16 + l15) * HD + c * 32 + quad * 8);

  f32x4 acc[4];
#pragma unroll
  for (int a = 0; a < 4; ++a) acc[a] = (f32x4){0.f, 0.f, 0.f, 0.f};

  if (z < 2) {
#pragma unroll
    for (int c = 0; c < 2; ++c)
#pragma unroll
      for (int mt = 0; mt < 4; ++mt) acc[mt] = MFMA(wf[mt][c], xf[c], acc[mt]);
    short* ob = ((z == 0) ? Qb : Kb) + ((size_t)nh * LSEQ + lrow) * HD;
#pragma unroll
    for (int mt = 0; mt < 4; ++mt)
      *(short4v*)&ob[mt * 16 + quad * 4] =
          pack4bf(acc[mt][0], acc[mt][1], acc[mt][2], acc[mt][3]);
  } else {
#pragma unroll
    for (int c = 0; c < 2; ++c)
#pragma unroll
      for (int nt = 0; nt < 4; ++nt) acc[nt] = MFMA(xf[c], wf[nt][c], acc[nt]);
    // C rows = l = l0 + wq*16 + quad*4 + r ; cols = d = nt*16+l15
#pragma unroll
    for (int nt = 0; nt < 4; ++nt)
      *(short4v*)&Vt[((size_t)nh * HD + nt * 16 + l15) * LSEQ + l0 + wq * 16 +
                     quad * 4] =
          pack4bf(acc[nt][0], acc[nt][1], acc[nt][2], acc[nt][3]);
  }
}

// ---------------------------------------------------------------------------
// Flash attention. Wave = 16 q; block = 4 waves = 64 q. Grid (32, 32) = 1024
// blocks -> 4 blocks/CU, 16 waves/CU. Single-buffered XOR-swizzled K/V LDS
// (25.6 KB); register prefetch of next tile + bias; no-max exp2 softmax;
// l via ones-MFMA; wave-private P tile.
__global__ __launch_bounds__(256, 4) void attn_kernel(
    const short* __restrict__ Qg,    // [nh][L][64] bf16 (Wq pre-scaled)
    const short* __restrict__ Kg,    // [nh][L][64] bf16
    const short* __restrict__ Vtg,   // [nh][64][L] bf16
    const float* __restrict__ biasf, // [N][L]: 0 or -1e30
    short* __restrict__ AO)          // [N*L][E] bf16
{
  __shared__ __align__(16) short Ks[64 * 64];
  __shared__ __align__(16) short Vs[64 * 64];
  __shared__ __align__(16) short Pl[4][16 * 72];

  const int t = threadIdx.x;
  const int wq = t >> 6, lane = t & 63;
  const int quad = lane >> 4, l15 = lane & 15;
  const int nh = blockIdx.y;
  const int n = nh >> 4, h = nh & 15;
  const int q0 = blockIdx.x * 64;

  // Q B-fragments for this wave's 16 q (q = l15)
  short8 qf[2];
#pragma unroll
  for (int c = 0; c < 2; ++c)
    qf[c] = *(const short8*)(Qg + ((size_t)nh * LSEQ + q0 + wq * 16 + l15) * HD +
                             c * 32 + quad * 8);

  // staging: 512 16B slots/tile; thread stages rows t>>3 and (t>>3)+32
  const int rowA = t >> 3, chA = t & 7, rowB = rowA + 32;
  const int ldsA = rowA * 64 + ((chA ^ (rowA & 7)) * 8);
  const int ldsB = rowB * 64 + ((chA ^ (rowB & 7)) * 8);
  const short* kbase = Kg + (size_t)nh * LSEQ * HD;
  const short* vbase = Vtg + (size_t)nh * HD * LSEQ;
  const float* bbase = biasf + n * LSEQ;

  short8 kr0 = *(const short8*)(kbase + (size_t)rowA * HD + chA * 8);
  short8 kr1 = *(const short8*)(kbase + (size_t)rowB * HD + chA * 8);
  short8 vr0 = *(const short8*)(vbase + (size_t)rowA * LSEQ + chA * 8);
  short8 vr1 = *(const short8*)(vbase + (size_t)rowB * LSEQ + chA * 8);
  f32x4 bcur[4];
#pragma unroll
  for (int mt = 0; mt < 4; ++mt)
    bcur[mt] = *(const f32x4*)(bbase + mt * 16 + quad * 4);

  *(short8*)&Ks[ldsA] = kr0;
  *(short8*)&Ks[ldsB] = kr1;
  *(short8*)&Vs[ldsA] = vr0;
  *(short8*)&Vs[ldsB] = vr1;
  __syncthreads();

  f32x4 O[4], Ol;
#pragma unroll
  for (int a = 0; a < 4; ++a) O[a] = (f32x4){0.f, 0.f, 0.f, 0.f};
  Ol = (f32x4){0.f, 0.f, 0.f, 0.f};
  const short one_bf = (short)0x3F80;
  const short8 ones = {one_bf, one_bf, one_bf, one_bf,
                       one_bf, one_bf, one_bf, one_bf};

  const int sw0 = ((0 * 4 + quad) ^ (l15 & 7)) * 8;
  const int sw1 = ((1 * 4 + quad) ^ (l15 & 7)) * 8;

  for (int kt = 0; kt < LSEQ / 64; ++kt) {
    f32x4 bnext[4];
    if (kt < LSEQ / 64 - 1) {
      const short* kb = kbase + (size_t)((kt + 1) * 64) * HD;
      kr0 = *(const short8*)(kb + (size_t)rowA * HD + chA * 8);
      kr1 = *(const short8*)(kb + (size_t)rowB * HD + chA * 8);
      const short* vb = vbase + (kt + 1) * 64;
      vr0 = *(const short8*)(vb + (size_t)rowA * LSEQ + chA * 8);
      vr1 = *(const short8*)(vb + (size_t)rowB * LSEQ + chA * 8);
      const float* bb = bbase + (kt + 1) * 64;
#pragma unroll
      for (int mt = 0; mt < 4; ++mt)
        bnext[mt] = *(const f32x4*)(bb + mt * 16 + quad * 4);
    }

    // ---- S^T = K·Q^T + bias: St[mt(k)][cols q]
    f32x4 St[4];
#pragma unroll
    for (int mt = 0; mt < 4; ++mt) St[mt] = bcur[mt];
#pragma unroll
    for (int c = 0; c < 2; ++c) {
      const int sw = c ? sw1 : sw0;
#pragma unroll
      for (int mt = 0; mt < 4; ++mt) {
        short8 kf = *(const short8*)&Ks[(mt * 16 + l15) * 64 + sw];
        St[mt] = MFMA(kf, qf[c], St[mt]);
      }
    }

    // ---- P = exp2(St); pack -> wave-private Pl[q][k]
#pragma unroll
    for (int mt = 0; mt < 4; ++mt) {
#pragma unroll
      for (int r = 0; r < 4; ++r) St[mt][r] = fexp2(St[mt][r]);
      *(short4v*)&Pl[wq][l15 * 72 + mt * 16 + quad * 4] =
          pack4bf(St[mt][0], St[mt][1], St[mt][2], St[mt][3]);
    }

    // ---- PV + l
#pragma unroll
    for (int c = 0; c < 2; ++c) {
      const int sw = c ? sw1 : sw0;
      short8 pf = *(const short8*)&Pl[wq][l15 * 72 + c * 32 + quad * 8];
#pragma unroll
      for (int ntv = 0; ntv < 4; ++ntv) {
        short8 vf = *(const short8*)&Vs[(ntv * 16 + l15) * 64 + sw];
        O[ntv] = MFMA(pf, vf, O[ntv]);
      }
      Ol = MFMA(pf, ones, Ol);
    }

    __syncthreads();  // all waves done reading Ks/Vs
    if (kt < LSEQ / 64 - 1) {
      *(short8*)&Ks[ldsA] = kr0;
      *(short8*)&Ks[ldsB] = kr1;
      *(short8*)&Vs[ldsA] = vr0;
      *(short8*)&Vs[ldsB] = vr1;
#pragma unroll
      for (int mt = 0; mt < 4; ++mt) bcur[mt] = bnext[mt];
    }
    __syncthreads();
  }

  // ---- epilogue: O/l -> bf16 AO[n*L + q][h*64 + dv]
  f32x4 inv;
#pragma unroll
  for (int r = 0; r < 4; ++r) inv[r] = 1.f / Ol[r];
  short* ob = AO + ((size_t)n * LSEQ + q0 + wq * 16) * EMB + h * HD;
#pragma unroll
  for (int ntv = 0; ntv < 4; ++ntv)
#pragma unroll
    for (int r = 0; r < 4; ++r)
      ob[(size_t)(quad * 4 + r) * EMB + ntv * 16 + l15] =
          bf16of(O[ntv][r] * inv[r]);
}

// ---------------------------------------------------------------------------
// Out-projection: C[r][j] = sum_e A[r][e]*Wo[j][e] + bo[j].
// 128x64 tile/block, grid (16,32)=512 -> 2 blocks/CU. XOR-swizzled LDS,
// double-buffered, register prefetch.
__global__ __launch_bounds__(256, 2) void outproj_mfma(
    const short* __restrict__ A, const short* __restrict__ W,
    const float* __restrict__ bo, float* __restrict__ C) {
  __shared__ __align__(16) short As[2][128 * 64];
  __shared__ __align__(16) short Bs[2][64 * 64];
  const int t = threadIdx.x;
  const int wq = t >> 6, lane = t & 63;
  const int quad = lane >> 4, l15 = lane & 15;
  const int j0 = blockIdx.x * 64, r0 = blockIdx.y * 128;

  f32x4 acc[2][4];
#pragma unroll
  for (int a = 0; a < 2; ++a)
#pragma unroll
    for (int b = 0; b < 4; ++b) acc[a][b] = (f32x4){0.f, 0.f, 0.f, 0.f};

  // A: 1024 slots (row = slot>>3, ch = slot&7); B: 512 slots.
  short8 ar[4], br[2];
#pragma unroll
  for (int i = 0; i < 4; ++i) {
    int slot = i * 256 + t, row = slot >> 3, ch = slot & 7;
    ar[i] = *(const short8*)(A + (size_t)(r0 + row) * EMB + ch * 8);
  }
#pragma unroll
  for (int i = 0; i < 2; ++i) {
    int slot = i * 256 + t, row = slot >> 3, ch = slot & 7;
    br[i] = *(const short8*)(W + (size_t)(j0 + row) * EMB + ch * 8);
  }
#pragma unroll
  for (int i = 0; i < 4; ++i) {
    int slot = i * 256 + t, row = slot >> 3, ch = slot & 7;
    *(short8*)&As[0][row * 64 + ((ch ^ (row & 7)) * 8)] = ar[i];
  }
#pragma unroll
  for (int i = 0; i < 2; ++i) {
    int slot = i * 256 + t, row = slot >> 3, ch = slot & 7;
    *(short8*)&Bs[0][row * 64 + ((ch ^ (row & 7)) * 8)] = br[i];
  }
  __syncthreads();

  const int sw0 = ((0 * 4 + quad) ^ (l15 & 7)) * 8;
  const int sw1 = ((1 * 4 + quad) ^ (l15 & 7)) * 8;

  for (int ek = 0; ek < EMB; ek += 64) {
    const int cur = (ek >> 6) & 1, nxt = cur ^ 1;
    if (ek + 64 < EMB) {
#pragma unroll
      for (int i = 0; i < 4; ++i) {
        int slot = i * 256 + t, row = slot >> 3, ch = slot & 7;
        ar[i] = *(const short8*)(A + (size_t)(r0 + row) * EMB + ek + 64 + ch * 8);
      }
#pragma unroll
      for (int i = 0; i < 2; ++i) {
        int slot = i * 256 + t, row = slot >> 3, ch = slot & 7;
        br[i] = *(const short8*)(W + (size_t)(j0 + row) * EMB + ek + 64 + ch * 8);
      }
    }
#pragma unroll
    for (int c = 0; c < 2; ++c) {
      const int sw = c ? sw1 : sw0;
      short8 af[2], bf[4];
#pragma unroll
      for (int mt = 0; mt < 2; ++mt)
        af[mt] = *(const short8*)&As[cur][(wq * 32 + mt * 16 + l15) * 64 + sw];
#pragma unroll
      for (int nt = 0; nt < 4; ++nt)
        bf[nt] = *(const short8*)&Bs[cur][(nt * 16 + l15) * 64 + sw];
#pragma unroll
      for (int mt = 0; mt < 2; ++mt)
#pragma unroll
        for (int nt = 0; nt < 4; ++nt)
          acc[mt][nt] = MFMA(af[mt], bf[nt], acc[mt][nt]);
    }
    if (ek + 64 < EMB) {
#pragma unroll
      for (int i = 0; i < 4; ++i) {
        int slot = i * 256 + t, row = slot >> 3, ch = slot & 7;
        *(short8*)&As[nxt][row * 64 + ((ch ^ (row & 7)) * 8)] = ar[i];
      }
#pragma unroll
      for (int i = 0; i < 2; ++i) {
        int slot = i * 256 + t, row = slot >> 3, ch = slot & 7;
        *(short8*)&Bs[nxt][row * 64 + ((ch ^ (row & 7)) * 8)] = br[i];
      }
    }
    __syncthreads();
  }

  float bn[4];
#pragma unroll
  for (int nt = 0; nt < 4; ++nt) bn[nt] = bo[j0 + nt * 16 + l15];
#pragma unroll
  for (int mt = 0; mt < 2; ++mt)
#pragma unroll
    for (int nt = 0; nt < 4; ++nt)
#pragma unroll
      for (int r = 0; r < 4; ++r)
        C[(size_t)(r0 + wq * 32 + mt * 16 + quad * 4 + r) * EMB + j0 +
          nt * 16 + l15] = acc[mt][nt][r] + bn[nt];
}

// ---------------------------------------------------------------------------
extern "C" void kernel_launch(void* const* d_in, const int* in_sizes, int n_in,
                              void* d_out, int out_size, void* d_ws,
                              size_t ws_size, hipStream_t stream) {
  const float* values = (const float*)d_in[0];
  const float* keys   = (const float*)d_in[1];
  const float* query  = (const float*)d_in[2];
  const int*   mask   = (const int*)d_in[3];
  const float* Wv     = (const float*)d_in[4];
  const float* Wk     = (const float*)d_in[5];
  const float* Wq     = (const float*)d_in[6];
  const float* Wo     = (const float*)d_in[7];
  const float* bo     = (const float*)d_in[8];
  float* out = (float*)d_out;

  short* ws = (short*)d_ws;
  const size_t tsz = (size_t)NB * NHEADS * LSEQ * HD;  // 4 Mi shorts
  short* Qb  = ws;
  short* Kb  = Qb + tsz;
  short* Vt  = Kb + tsz;
  short* AOb = Vt + tsz;
  short* Wob = AOb + tsz;               // 1 Mi shorts
  float* biasf = (float*)(Wob + (size_t)EMB * EMB);  // 4096 floats
  short* Wqb = (short*)(biasf + NB * LSEQ);
  short* Wkb = Wqb + HD * HD;
  short* Wvb = Wkb + HD * HD;

  dim3 blk(256);
  conv_kernel<<<dim3(1024), blk, 0, stream>>>(Wq, Wk, Wv, Wo, mask, Wqb, Wkb,
                                              Wvb, Wob, biasf);
  proj_mfma<<<dim3(LSEQ / 64, NB * NHEADS, 3), blk, 0, stream>>>(
      query, keys, values, Wqb, Wkb, Wvb, Qb, Kb, Vt);
  attn_kernel<<<dim3(LSEQ / 64, NB * NHEADS), blk, 0, stream>>>(Qb, Kb, Vt,
                                                                biasf, AOb);
  outproj_mfma<<<dim3(EMB / 64, NB * LSEQ / 128), blk, 0, stream>>>(AOb, Wob,
                                                                    bo, out);
}